// Round 20
// baseline (55.880 us; speedup 1.0000x reference)
//
#include <hip/hip_runtime.h>

#define BB    4
#define NN    8192
#define KK    16
#define CIN   64
#define COUTC 64
#define P     16           // points per block (= MFMA M-tile)

typedef short bf16x8 __attribute__((ext_vector_type(8)));
typedef float f32x4  __attribute__((ext_vector_type(4)));
typedef float f32x2  __attribute__((ext_vector_type(2)));

__device__ __forceinline__ unsigned short f2bf_rne(float f) {
    unsigned int u = __builtin_bit_cast(unsigned int, f);
    u += 0x7fffu + ((u >> 16) & 1u);
    return (unsigned short)(u >> 16);
}

__device__ __forceinline__ unsigned int pack_bf2(float lo, float hi) {
    return (unsigned int)f2bf_rne(lo) | ((unsigned int)f2bf_rne(hi) << 16);
}

// ---- fused prep (258 blocks): [0,256) Wt ; 256 fold ; 257 Wt2/Wt3 ----
__global__ __launch_bounds__(256) void prep_all(
    const float* __restrict__ W, unsigned short* __restrict__ Wt,
    const float* __restrict__ l1w, const float* __restrict__ l1b,
    const float* __restrict__ centers, float* __restrict__ A1,
    const float* __restrict__ l2w, const float* __restrict__ l3w,
    unsigned short* __restrict__ Wt2, unsigned short* __restrict__ Wt3)
{
    const int blk = blockIdx.x;
    const int t   = threadIdx.x;
    if (blk < 256) {
        const int o    = blk * 256 + t;                // 65536 total
        const int cout = o >> 10;
        const int kp   = o & 1023;
        const int m    = kp >> 6;
        const int cin  = kp & 63;
        Wt[o] = f2bf_rne(W[(cin * 16 + m) * 64 + cout] * (1.0f / 16.0f));
    } else if (blk == 256) {
        if (t < 32) {
            float bb = l1b[t];
            float a0 = 0.f, a1 = 0.f, a2 = 0.f;
            for (int c = 0; c < 16; ++c) {
                const float w0 = l1w[(c     ) * 32 + t];
                const float w1 = l1w[(16 + c) * 32 + t];
                const float w2 = l1w[(32 + c) * 32 + t];
                a0 += w0; a1 += w1; a2 += w2;
                bb -= centers[c] * w0 + centers[16 + c] * w1 + centers[32 + c] * w2;
            }
            A1[0 * 32 + t] = a0; A1[1 * 32 + t] = a1; A1[2 * 32 + t] = a2; A1[3 * 32 + t] = bb;
        }
    } else {
        // Wt2[l*8+j] = l2w[k][col], k=(l>>4)*8+j, col=l&15   (B-frag, K=32)
        // Wt3[l*8+j] = k<16 ? l3w[k][col] : 0                (B-frag, K=16 zero-padded)
        for (int i = t; i < 1024; i += 256) {
            if (i < 512) {
                const int l = i >> 3, j = i & 7;
                const int k = (l >> 4) * 8 + j, col = l & 15;
                Wt2[i] = f2bf_rne(l2w[k * 16 + col]);
            } else {
                const int i3 = i - 512;
                const int l = i3 >> 3, j = i3 & 7;
                const int k = (l >> 4) * 8 + j, col = l & 15;
                Wt3[i3] = (k < 16) ? f2bf_rne(l3w[k * 16 + col]) : (unsigned short)0;
            }
        }
    }
}

__global__ __launch_bounds__(256) void ptconv_fused(
    const float* __restrict__ inp,       // [B,N,CIN] f32 (gathered directly)
    const float* __restrict__ points,    // [B,N,3]
    const float* __restrict__ next_pts,  // [B,N,3]
    const int*   __restrict__ indices,   // [B,N,K]
    const unsigned short* __restrict__ Wt,  // [COUT][1024] bf16 (prep)
    const unsigned short* __restrict__ Wt2, // [64][8] bf16 layer-2 B-frag
    const unsigned short* __restrict__ Wt3, // [64][8] bf16 layer-3 B-frag (zero-pad)
    const float* __restrict__ A1f,       // [4][32] folded layer-1 (prep, SoA)
    const float* __restrict__ bias,      // [COUT]
    const float* __restrict__ l2b, const float* __restrict__ l3b,
    float* __restrict__ out)             // [B,N,COUT]
{
    const int t    = threadIdx.x;
    const int lane = t & 63;
    const int w    = t >> 6;             // wave id 0..3
    const int pt0  = blockIdx.x * P;
    const int b    = pt0 >> 13;          // pt0 / NN

    // 32 KB: 16 windows of 2048 B (one per point). Wave w owns windows w*4..w*4+3
    // (bytes [w*8192,(w+1)*8192)) until the single barrier.
    // Lifecycle per wave region (same-wave read -> fence -> overwrite, one array):
    //   H1 rows (64B/row, [0,4096))  ->  L2 A-reads -> fence -> H2 overlay ([0,2048))
    //   ->  L3 A-reads -> fence -> h3t overlay (window T, first ~544B)
    //   ->  phase-2 reads h3t, then writes f: even half [win, win+1024),
    //       odd half [win+1024, win+2048).  Phase 3 (after barrier) is read-only.
    __shared__ unsigned short s_u[P][1024];       // 32 KB

    char* const wb = (char*)s_u + w * 8192;       // wave region base
    const f32x2 zero2 = {0.f, 0.f};
    const f32x4 z4 = {0.f, 0.f, 0.f, 0.f};
    const int arow = lane & 15;
    const int hi   = lane >> 4;

    // ---------------- stage 1a: h1 per thread (row = t = p*16+k), pack, H1 -> LDS ----------------
    {
        const int p = t >> 4;
        const int pt = pt0 + p;
        const int id = indices[(size_t)pt0 * KK + t];  // coalesced
        const float* pp = points + ((size_t)(b * NN + id)) * 3;
        const float* np = next_pts + (size_t)pt * 3;
        const float px = pp[0] - np[0];
        const float py = pp[1] - np[1];
        const float pz = pp[2] - np[2];
        const f32x2 px2 = {px, px}, py2 = {py, py}, pz2 = {pz, pz};

        const f32x2* A0  = (const f32x2*)(A1f);
        const f32x2* A1v = (const f32x2*)(A1f + 32);
        const f32x2* A2  = (const f32x2*)(A1f + 64);
        const f32x2* A3  = (const f32x2*)(A1f + 96);
        unsigned int pk[16];
        #pragma unroll
        for (int j = 0; j < 16; ++j) {
            f32x2 a = __builtin_elementwise_fma(pz2, A2[j], A3[j]);
            a = __builtin_elementwise_fma(py2, A1v[j], a);
            a = __builtin_elementwise_fma(px2, A0[j], a);
            a = __builtin_elementwise_max(a, zero2);
            pk[j] = pack_bf2(a[0], a[1]);          // h1 units 2j, 2j+1 (bf16)
        }
        // H1 row r'=lane, chunk c: addr = r'*64 + (c*16 ^ ((r'&3)<<4)) — key bits 4-5 only
        #pragma unroll
        for (int c = 0; c < 4; ++c) {
            const unsigned int off = (unsigned)(lane * 64)
                + ((((unsigned)c) * 16u) ^ (((unsigned)(lane & 3)) << 4));
            *(uint4*)(wb + off) = make_uint4(pk[4*c], pk[4*c+1], pk[4*c+2], pk[4*c+3]);
        }
    }
    __threadfence_block();

    // ---------------- stage 1b: layer 2 via MFMA (4 row-tiles); defer H2 overlay ----------------
    {
        const bf16x8 b2 = *(const bf16x8*)(Wt2 + lane * 8);
        const float bias2 = l2b[arow];             // D col = l&15 = h2 unit
        uint2 h2sv[4];
        #pragma unroll
        for (int T = 0; T < 4; ++T) {
            const int row = T * 16 + arow;         // local row, k-slice = hi
            const unsigned int off = (unsigned)(row * 64)
                + ((((unsigned)hi) * 16u) ^ (((unsigned)(row & 3)) << 4));
            const bf16x8 a = *(const bf16x8*)(wb + off);
            const f32x4 d = __builtin_amdgcn_mfma_f32_16x16x32_bf16(a, b2, z4, 0, 0, 0);
            h2sv[T].x = pack_bf2(fmaxf(d[0] + bias2, 0.f), fmaxf(d[1] + bias2, 0.f));
            h2sv[T].y = pack_bf2(fmaxf(d[2] + bias2, 0.f), fmaxf(d[3] + bias2, 0.f));
        }
        __threadfence_block();                     // all H1 reads retired before H2 overlay
        // D: unit=arow, local rows T*16 + hi*4 + reg.  H2: (R*32 + u*2) ^ ((R&1)<<4)
        #pragma unroll
        for (int T = 0; T < 4; ++T) {
            const unsigned short v0 = (unsigned short)(h2sv[T].x & 0xffffu);
            const unsigned short v1 = (unsigned short)(h2sv[T].x >> 16);
            const unsigned short v2 = (unsigned short)(h2sv[T].y & 0xffffu);
            const unsigned short v3 = (unsigned short)(h2sv[T].y >> 16);
            const int R0 = T * 16 + hi * 4;
            *(unsigned short*)(wb + ((unsigned)((R0+0) * 32 + arow * 2) ^ (((unsigned)((R0+0) & 1)) << 4))) = v0;
            *(unsigned short*)(wb + ((unsigned)((R0+1) * 32 + arow * 2) ^ (((unsigned)((R0+1) & 1)) << 4))) = v1;
            *(unsigned short*)(wb + ((unsigned)((R0+2) * 32 + arow * 2) ^ (((unsigned)((R0+2) & 1)) << 4))) = v2;
            *(unsigned short*)(wb + ((unsigned)((R0+3) * 32 + arow * 2) ^ (((unsigned)((R0+3) & 1)) << 4))) = v3;
        }
    }
    __threadfence_block();

    // ---------------- stage 1d/1e: layer 3 via MFMA (K zero-padded), h3t overlay ----------------
    {
        const bf16x8 b3 = *(const bf16x8*)(Wt3 + lane * 8);   // zeros for k>=16
        const float bias3 = l3b[arow];
        uint2 hsave[4];                             // defer writes until all H2 reads done
        #pragma unroll
        for (int T = 0; T < 4; ++T) {
            const int row = T * 16 + arow;
            const unsigned int off = ((unsigned)(row * 32 + hi * 16)) ^ (((unsigned)(row & 1)) << 4);
            const bf16x8 a = *(const bf16x8*)(wb + off);      // hi>=2 reads junk; b3=0 there
            const f32x4 d = __builtin_amdgcn_mfma_f32_16x16x32_bf16(a, b3, z4, 0, 0, 0);
            hsave[T].x = pack_bf2(fmaxf(d[0] + bias3, 0.f), fmaxf(d[1] + bias3, 0.f));
            hsave[T].y = pack_bf2(fmaxf(d[2] + bias3, 0.f), fmaxf(d[3] + bias3, 0.f));
        }
        __threadfence_block();                      // all H2 reads retired before h3t overlay
        // h3t: window T at T*2048; byte m*32 + k*2 ^ ((T&3)<<5); m=arow, k = hi*4+reg
        #pragma unroll
        for (int T = 0; T < 4; ++T) {
            const unsigned int xw = ((unsigned)(T & 3)) << 5;
            const unsigned int base = (unsigned)(T * 2048 + arow * 32 + hi * 8);
            *(uint2*)(wb + (base ^ xw)) = make_uint2(hsave[T].x, hsave[T].y);
        }
    }
    __threadfence_block();

    // ---------------- phase 2: f = feats @ h3 via MFMA; BOTH halves -> LDS ----------------
    {
        const int kg = (hi & 1) * 8;
        const float* inb = inp + (size_t)b * NN * 64;
        const int* idxg = indices + (size_t)pt0 * KK;
        const bf16x8 vzero = {0, 0, 0, 0, 0, 0, 0, 0};
        char* fbb = (char*)s_u;

        #pragma unroll
        for (int pr = 0; pr < 2; ++pr) {
            const int pA  = w * 4 + pr * 2;
            const int pB  = pA + 1;
            const int myp = (hi < 2) ? pA : pB;

            const int4 i0 = *(const int4*)&idxg[myp * 16 + kg];
            const int4 i1 = *(const int4*)&idxg[myp * 16 + kg + 4];
            const int ids[8] = {i0.x, i0.y, i0.z, i0.w, i1.x, i1.y, i1.z, i1.w};

            // direct f32 gather: per row 4 floats (one per tile), lanes 0-15 = one 64B line
            float rf0[8], rf1[8], rf2[8], rf3[8];
            #pragma unroll
            for (int jj = 0; jj < 8; ++jj) {
                const float* rp = inb + (size_t)ids[jj] * 64 + arow;
                rf0[jj] = rp[0];  rf1[jj] = rp[16];
                rf2[jj] = rp[32]; rf3[jj] = rp[48];
            }

            // read h3t BEFORE overwriting this window with f
            const unsigned int hb = ((unsigned)(myp * 2048 + arow * 32 + kg * 2))
                                    ^ (((unsigned)(myp & 3)) << 5);
            const bf16x8 vfull = *(const bf16x8*)((const char*)s_u + hb);
            const bf16x8 bfA = (hi < 2) ? vfull : vzero;
            const bf16x8 bfB = (hi < 2) ? vzero : vfull;

            #pragma unroll
            for (int tile = 0; tile < 4; ++tile) {
                bf16x8 af;
                #pragma unroll
                for (int jj = 0; jj < 8; ++jj) {
                    const float v = (tile == 0) ? rf0[jj] : (tile == 1) ? rf1[jj]
                                  : (tile == 2) ? rf2[jj] : rf3[jj];
                    af[jj] = (short)f2bf_rne(v);
                }
                const f32x4 dA = __builtin_amdgcn_mfma_f32_16x16x32_bf16(af, bfA, z4, 0, 0, 0);
                const f32x4 dB = __builtin_amdgcn_mfma_f32_16x16x32_bf16(af, bfB, z4, 0, 0, 0);
                const uint2 vA = make_uint2(pack_bf2(dA[0], dA[1]), pack_bf2(dA[2], dA[3]));
                const uint2 vB = make_uint2(pack_bf2(dB[0], dB[1]), pack_bf2(dB[2], dB[3]));
                // even half (tiles 0,1) at window+0 ; odd half (tiles 2,3) at window+1024
                const unsigned int half = (tile < 2) ? 0u : 1024u;
                const unsigned int baseo = (unsigned)(arow * 64 + (tile & 1) * 32 + hi * 8);
                const unsigned int offA = ((unsigned)(pA * 2048) + half + baseo)
                                          ^ (((unsigned)((pA & 7) ^ (arow & 7))) << 4);
                const unsigned int offB = ((unsigned)(pB * 2048) + half + baseo)
                                          ^ (((unsigned)((pB & 7) ^ (arow & 7))) << 4);
                *(uint2*)(fbb + offA) = vA;
                *(uint2*)(fbb + offB) = vB;
            }
        }
    }
    __syncthreads();                      // the ONLY barrier

    // ---------------- phase 3: 32 k-steps straight through (read-only) ----------------
    {
        const unsigned short* wtb = Wt + (size_t)(w * 16 + arow) * 1024 + hi * 8;
        const char* fbb = (const char*)s_u;
        f32x4 acc = {0.f, 0.f, 0.f, 0.f};

        #pragma unroll
        for (int m = 0; m < 16; ++m) {   // even kk = 2m  (cin 0..31)
            const unsigned int xr = ((unsigned)((arow & 7) ^ (m & 7))) << 4;
            const bf16x8 av = *(const bf16x8*)(fbb +
                (((unsigned)(arow * 2048 + m * 64 + hi * 16)) ^ xr));
            const bf16x8 bv = *(const bf16x8*)(wtb + m * 64);
            acc = __builtin_amdgcn_mfma_f32_16x16x32_bf16(av, bv, acc, 0, 0, 0);
        }
        #pragma unroll
        for (int m = 0; m < 16; ++m) {   // odd kk = 2m+1  (cin 32..63)
            const unsigned int xr = ((unsigned)((arow & 7) ^ (m & 7))) << 4;
            const bf16x8 av = *(const bf16x8*)(fbb +
                (((unsigned)(arow * 2048 + 1024 + m * 64 + hi * 16)) ^ xr));
            const bf16x8 bv = *(const bf16x8*)(wtb + m * 64 + 32);
            acc = __builtin_amdgcn_mfma_f32_16x16x32_bf16(av, bv, acc, 0, 0, 0);
        }

        const float bvs = bias[w * 16 + arow];
        #pragma unroll
        for (int r = 0; r < 4; ++r) {
            const int prow = hi * 4 + r;
            out[((size_t)(pt0 + prow)) * 64 + w * 16 + arow] = acc[r] + bvs;
        }
    }
}

extern "C" void kernel_launch(void* const* d_in, const int* in_sizes, int n_in,
                              void* d_out, int out_size, void* d_ws, size_t ws_size,
                              hipStream_t stream) {
    const float* inp      = (const float*)d_in[0];
    const float* points   = (const float*)d_in[1];
    const float* next_pts = (const float*)d_in[2];
    const int*   indices  = (const int*)  d_in[3];
    const float* weight   = (const float*)d_in[4];
    const float* bias     = (const float*)d_in[5];
    const float* centers  = (const float*)d_in[6];
    const float* l1w      = (const float*)d_in[7];
    const float* l1b      = (const float*)d_in[8];
    const float* l2w      = (const float*)d_in[9];
    const float* l2b      = (const float*)d_in[10];
    const float* l3w      = (const float*)d_in[11];
    const float* l3b      = (const float*)d_in[12];
    float* outp = (float*)d_out;

    unsigned short* Wt    = (unsigned short*)d_ws;                  // 128 KB @ 0
    float*          A1f   = (float*)((char*)d_ws + 131072);         // 512 B
    unsigned short* Wt2   = (unsigned short*)((char*)d_ws + 132096);// 1 KB
    unsigned short* Wt3   = (unsigned short*)((char*)d_ws + 133120);// 1 KB

    prep_all<<<258, 256, 0, stream>>>(weight, Wt, l1w, l1b, centers, A1f,
                                      l2w, l3w, Wt2, Wt3);

    const int grid = (BB * NN) / P;               // 2048 blocks
    ptconv_fused<<<grid, 256, 0, stream>>>(inp, points, next_pts, indices,
                                           Wt, Wt2, Wt3, A1f, bias,
                                           l2b, l3b, outp);
}

// Round 21
// 52.807 us; speedup vs baseline: 1.0582x; 1.0582x over previous
//
#include <hip/hip_runtime.h>

#define BB    4
#define NN    8192
#define KK    16
#define CIN   64
#define COUTC 64
#define P     16           // points per block (= MFMA M-tile)

typedef short bf16x8 __attribute__((ext_vector_type(8)));
typedef float f32x4  __attribute__((ext_vector_type(4)));
typedef float f32x2  __attribute__((ext_vector_type(2)));
typedef unsigned short u16x4 __attribute__((ext_vector_type(4)));

__device__ __forceinline__ unsigned short f2bf_rne(float f) {
    unsigned int u = __builtin_bit_cast(unsigned int, f);
    u += 0x7fffu + ((u >> 16) & 1u);
    return (unsigned short)(u >> 16);
}

__device__ __forceinline__ unsigned int pack_bf2(float lo, float hi) {
    return (unsigned int)f2bf_rne(lo) | ((unsigned int)f2bf_rne(hi) << 16);
}

// ---- fused prep ----
// [0,2048): inp->bf16 tile-transposed, 4 outputs/thread:
//   inp_bf[n*64 + r*4 + t4] = inp[n*64 + t4*16 + r]
// [2048,2304): Wt ; 2304: layer-1 fold ; 2305: Wt2/Wt3 lane-major MFMA B-frags
__global__ __launch_bounds__(256) void prep_all(
    const float* __restrict__ inp, unsigned short* __restrict__ inp_bf,
    const float* __restrict__ W, unsigned short* __restrict__ Wt,
    const float* __restrict__ l1w, const float* __restrict__ l1b,
    const float* __restrict__ centers, float* __restrict__ A1,
    const float* __restrict__ l2w, const float* __restrict__ l3w,
    unsigned short* __restrict__ Wt2, unsigned short* __restrict__ Wt3)
{
    const int blk = blockIdx.x;
    const int t   = threadIdx.x;
    if (blk < 2048) {
        const int q4 = blk * 256 + t;                  // 524288 quads
        const int n  = q4 >> 4;
        const int r  = q4 & 15;
        const float* src = inp + (size_t)n * 64 + r;
        u16x4 v;
        v[0] = f2bf_rne(src[0]);
        v[1] = f2bf_rne(src[16]);
        v[2] = f2bf_rne(src[32]);
        v[3] = f2bf_rne(src[48]);
        *(u16x4*)(inp_bf + (size_t)n * 64 + r * 4) = v;
    } else if (blk < 2304) {
        const int o    = (blk - 2048) * 256 + t;       // 65536 total
        const int cout = o >> 10;
        const int kp   = o & 1023;
        const int m    = kp >> 6;
        const int cin  = kp & 63;
        Wt[o] = f2bf_rne(W[(cin * 16 + m) * 64 + cout] * (1.0f / 16.0f));
    } else if (blk == 2304) {
        if (t < 32) {
            float bb = l1b[t];
            float a0 = 0.f, a1 = 0.f, a2 = 0.f;
            for (int c = 0; c < 16; ++c) {
                const float w0 = l1w[(c     ) * 32 + t];
                const float w1 = l1w[(16 + c) * 32 + t];
                const float w2 = l1w[(32 + c) * 32 + t];
                a0 += w0; a1 += w1; a2 += w2;
                bb -= centers[c] * w0 + centers[16 + c] * w1 + centers[32 + c] * w2;
            }
            A1[0 * 32 + t] = a0; A1[1 * 32 + t] = a1; A1[2 * 32 + t] = a2; A1[3 * 32 + t] = bb;
        }
    } else {
        // Wt2[l*8+j] = l2w[k][col], k=(l>>4)*8+j, col=l&15   (B-frag, K=32)
        // Wt3[l*8+j] = k<16 ? l3w[k][col] : 0                (B-frag, K=16 zero-padded)
        for (int i = t; i < 1024; i += 256) {
            if (i < 512) {
                const int l = i >> 3, j = i & 7;
                const int k = (l >> 4) * 8 + j, col = l & 15;
                Wt2[i] = f2bf_rne(l2w[k * 16 + col]);
            } else {
                const int i3 = i - 512;
                const int l = i3 >> 3, j = i3 & 7;
                const int k = (l >> 4) * 8 + j, col = l & 15;
                Wt3[i3] = (k < 16) ? f2bf_rne(l3w[k * 16 + col]) : (unsigned short)0;
            }
        }
    }
}

__global__ __launch_bounds__(256) void ptconv_fused(
    const unsigned short* __restrict__ inp_bf, // [B,N,16,4] bf16 tile-transposed (prep)
    const float* __restrict__ points,    // [B,N,3]
    const float* __restrict__ next_pts,  // [B,N,3]
    const int*   __restrict__ indices,   // [B,N,K]
    const unsigned short* __restrict__ Wt,  // [COUT][1024] bf16 (prep)
    const unsigned short* __restrict__ Wt2, // [64][8] bf16 layer-2 B-frag
    const unsigned short* __restrict__ Wt3, // [64][8] bf16 layer-3 B-frag (zero-pad)
    const float* __restrict__ A1f,       // [4][32] folded layer-1 (prep, SoA)
    const float* __restrict__ bias,      // [COUT]
    const float* __restrict__ l2b, const float* __restrict__ l3b,
    float* __restrict__ out)             // [B,N,COUT]
{
    const int t    = threadIdx.x;
    const int lane = t & 63;
    const int w    = t >> 6;             // wave id 0..3
    const int pt0  = blockIdx.x * P;
    const int b    = pt0 >> 13;          // pt0 / NN

    // ONE 16 KB buffer; wave w owns bytes [w*4096, (w+1)*4096) until the phase-3 barrier.
    // Lifecycle (strict same-wave read -> fence -> overwrite, single may-alias array):
    //   H1 rows (64B/row, key (row&3)<<4)  ->  L2 A-reads  -> fence -> H2 overlay (32B/row)
    //   ->  L3 A-reads  -> fence ->  h3t windows overlay  ->  phase-2 reads
    //   ->  f even-half overlay.  Phase 3 reads cross-wave after barrier.
    __shared__ unsigned short s_u[P][512];        // 16 KB

    char* const wb = (char*)s_u + w * 4096;       // wave region base
    const f32x2 zero2 = {0.f, 0.f};
    const f32x4 z4 = {0.f, 0.f, 0.f, 0.f};
    const int arow = lane & 15;
    const int hi   = lane >> 4;

    // ---------------- stage 1a: h1 per thread (row = t = p*16+k), pack, H1 -> LDS ----------------
    {
        const int p = t >> 4;
        const int pt = pt0 + p;
        const int id = indices[(size_t)pt0 * KK + t];  // coalesced
        const float* pp = points + ((size_t)(b * NN + id)) * 3;
        const float* np = next_pts + (size_t)pt * 3;
        const float px = pp[0] - np[0];
        const float py = pp[1] - np[1];
        const float pz = pp[2] - np[2];
        const f32x2 px2 = {px, px}, py2 = {py, py}, pz2 = {pz, pz};

        const f32x2* A0  = (const f32x2*)(A1f);
        const f32x2* A1v = (const f32x2*)(A1f + 32);
        const f32x2* A2  = (const f32x2*)(A1f + 64);
        const f32x2* A3  = (const f32x2*)(A1f + 96);
        unsigned int pk[16];
        #pragma unroll
        for (int j = 0; j < 16; ++j) {
            f32x2 a = __builtin_elementwise_fma(pz2, A2[j], A3[j]);
            a = __builtin_elementwise_fma(py2, A1v[j], a);
            a = __builtin_elementwise_fma(px2, A0[j], a);
            a = __builtin_elementwise_max(a, zero2);
            pk[j] = pack_bf2(a[0], a[1]);          // h1 units 2j, 2j+1 (bf16)
        }
        // H1 row r'=lane, chunk c: addr = r'*64 + (c*16 ^ ((r'&3)<<4)) — key bits 4-5 only
        #pragma unroll
        for (int c = 0; c < 4; ++c) {
            const unsigned int off = (unsigned)(lane * 64)
                + ((((unsigned)c) * 16u) ^ (((unsigned)(lane & 3)) << 4));
            *(uint4*)(wb + off) = make_uint4(pk[4*c], pk[4*c+1], pk[4*c+2], pk[4*c+3]);
        }
    }
    __threadfence_block();

    // ---------------- stage 1b: layer 2 via MFMA (4 row-tiles); defer H2 overlay ----------------
    {
        const bf16x8 b2 = *(const bf16x8*)(Wt2 + lane * 8);
        const float bias2 = l2b[arow];             // D col = l&15 = h2 unit
        uint2 h2sv[4];
        #pragma unroll
        for (int T = 0; T < 4; ++T) {
            const int row = T * 16 + arow;         // local row, k-slice = hi
            const unsigned int off = (unsigned)(row * 64)
                + ((((unsigned)hi) * 16u) ^ (((unsigned)(row & 3)) << 4));
            const bf16x8 a = *(const bf16x8*)(wb + off);
            const f32x4 d = __builtin_amdgcn_mfma_f32_16x16x32_bf16(a, b2, z4, 0, 0, 0);
            h2sv[T].x = pack_bf2(fmaxf(d[0] + bias2, 0.f), fmaxf(d[1] + bias2, 0.f));
            h2sv[T].y = pack_bf2(fmaxf(d[2] + bias2, 0.f), fmaxf(d[3] + bias2, 0.f));
        }
        __threadfence_block();                     // all H1 reads retired before H2 overlay
        // D: unit=arow, local rows T*16 + hi*4 + reg.  H2: (R*32 + u*2) ^ ((R&1)<<4)
        #pragma unroll
        for (int T = 0; T < 4; ++T) {
            const unsigned short v0 = (unsigned short)(h2sv[T].x & 0xffffu);
            const unsigned short v1 = (unsigned short)(h2sv[T].x >> 16);
            const unsigned short v2 = (unsigned short)(h2sv[T].y & 0xffffu);
            const unsigned short v3 = (unsigned short)(h2sv[T].y >> 16);
            const int R0 = T * 16 + hi * 4;
            *(unsigned short*)(wb + ((unsigned)((R0+0) * 32 + arow * 2) ^ (((unsigned)((R0+0) & 1)) << 4))) = v0;
            *(unsigned short*)(wb + ((unsigned)((R0+1) * 32 + arow * 2) ^ (((unsigned)((R0+1) & 1)) << 4))) = v1;
            *(unsigned short*)(wb + ((unsigned)((R0+2) * 32 + arow * 2) ^ (((unsigned)((R0+2) & 1)) << 4))) = v2;
            *(unsigned short*)(wb + ((unsigned)((R0+3) * 32 + arow * 2) ^ (((unsigned)((R0+3) & 1)) << 4))) = v3;
        }
    }
    __threadfence_block();

    // ---------------- stage 1d/1e: layer 3 via MFMA (K zero-padded), h3t overlay ----------------
    {
        const bf16x8 b3 = *(const bf16x8*)(Wt3 + lane * 8);   // zeros for k>=16
        const float bias3 = l3b[arow];
        uint2 hsave[4];                             // defer writes until all H2 reads done
        #pragma unroll
        for (int T = 0; T < 4; ++T) {
            const int row = T * 16 + arow;
            const unsigned int off = ((unsigned)(row * 32 + hi * 16)) ^ (((unsigned)(row & 1)) << 4);
            const bf16x8 a = *(const bf16x8*)(wb + off);      // hi>=2 reads junk; b3=0 there
            const f32x4 d = __builtin_amdgcn_mfma_f32_16x16x32_bf16(a, b3, z4, 0, 0, 0);
            hsave[T].x = pack_bf2(fmaxf(d[0] + bias3, 0.f), fmaxf(d[1] + bias3, 0.f));
            hsave[T].y = pack_bf2(fmaxf(d[2] + bias3, 0.f), fmaxf(d[3] + bias3, 0.f));
        }
        __threadfence_block();                      // all H2 reads retired before h3t overlay
        // h3t: window p=w*4+T, byte m*32 + k*2 ^ ((p&3)<<5); m=arow, k = hi*4+reg.
        // The 4 u16 (k offsets 0,2,4,6) are contiguous; XOR key is bits>=5 -> one b64 store.
        #pragma unroll
        for (int T = 0; T < 4; ++T) {
            const unsigned int xw = ((unsigned)(T & 3)) << 5;
            const unsigned int base = (unsigned)(T * 1024 + arow * 32 + hi * 8);
            *(uint2*)(wb + (base ^ xw)) = make_uint2(hsave[T].x, hsave[T].y);
        }
    }
    __threadfence_block();

    // ---------------- phase 2: f = feats @ h3 via MFMA (r14 verbatim) ----------------
    uint2 holdA[2][2], holdB[2][2];
    {
        const int kg   = (hi & 1) * 8;
        const unsigned short* ibase = inp_bf + (size_t)b * NN * 64;
        const int* idxg = indices + (size_t)pt0 * KK;
        const bf16x8 vzero = {0, 0, 0, 0, 0, 0, 0, 0};
        char* fbb = (char*)s_u;

        #pragma unroll
        for (int pr = 0; pr < 2; ++pr) {
            const int pA  = w * 4 + pr * 2;
            const int pB  = pA + 1;
            const int myp = (hi < 2) ? pA : pB;

            const int4 i0 = *(const int4*)&idxg[myp * 16 + kg];
            const int4 i1 = *(const int4*)&idxg[myp * 16 + kg + 4];
            const int ids[8] = {i0.x, i0.y, i0.z, i0.w, i1.x, i1.y, i1.z, i1.w};

            u16x4 rows[8];
            #pragma unroll
            for (int jj = 0; jj < 8; ++jj)
                rows[jj] = *(const u16x4*)(ibase + (size_t)ids[jj] * 64 + arow * 4);

            const unsigned int hb = ((unsigned)(myp * 1024 + arow * 32 + kg * 2))
                                    ^ (((unsigned)(myp & 3)) << 5);
            const bf16x8 vfull = *(const bf16x8*)((const char*)s_u + hb);
            const bf16x8 bfA = (hi < 2) ? vfull : vzero;
            const bf16x8 bfB = (hi < 2) ? vzero : vfull;

            #pragma unroll
            for (int tile = 0; tile < 4; ++tile) {
                bf16x8 af;
                #pragma unroll
                for (int jj = 0; jj < 8; ++jj) af[jj] = (short)rows[jj][tile];
                const f32x4 dA = __builtin_amdgcn_mfma_f32_16x16x32_bf16(af, bfA, z4, 0, 0, 0);
                const f32x4 dB = __builtin_amdgcn_mfma_f32_16x16x32_bf16(af, bfB, z4, 0, 0, 0);
                const uint2 vA = make_uint2(pack_bf2(dA[0], dA[1]), pack_bf2(dA[2], dA[3]));
                const uint2 vB = make_uint2(pack_bf2(dB[0], dB[1]), pack_bf2(dB[2], dB[3]));
                if (tile < 2) {
                    const unsigned int baseo = (unsigned)(arow * 64 + tile * 32 + hi * 8);
                    const unsigned int offA = ((unsigned)(pA * 1024) + baseo)
                                              ^ (((unsigned)((pA & 7) ^ (arow & 7))) << 4);
                    const unsigned int offB = ((unsigned)(pB * 1024) + baseo)
                                              ^ (((unsigned)((pB & 7) ^ (arow & 7))) << 4);
                    *(uint2*)(fbb + offA) = vA;
                    *(uint2*)(fbb + offB) = vB;
                } else {
                    holdA[pr][tile - 2] = vA;
                    holdB[pr][tile - 2] = vB;
                }
            }
        }
    }
    __syncthreads();

    // ---------------- phase 3: even k-pass, swap halves, odd k-pass (r14 verbatim) ----------------
    {
        const unsigned short* wtb = Wt + (size_t)(w * 16 + arow) * 1024 + hi * 8;
        const char* fbb = (const char*)s_u;
        f32x4 acc = {0.f, 0.f, 0.f, 0.f};

        #pragma unroll
        for (int m = 0; m < 16; ++m) {   // even kk = 2m  (cin 0..31)
            const unsigned int xr = ((unsigned)((arow & 7) ^ (m & 7))) << 4;
            const bf16x8 av = *(const bf16x8*)(fbb +
                (((unsigned)(arow * 1024 + m * 64 + hi * 16)) ^ xr));
            const bf16x8 bv = *(const bf16x8*)(wtb + m * 64);
            acc = __builtin_amdgcn_mfma_f32_16x16x32_bf16(av, bv, acc, 0, 0, 0);
        }
        __syncthreads();

        {   // write odd half (cin 32..63) from hold regs
            char* fbw = (char*)s_u;
            #pragma unroll
            for (int pr = 0; pr < 2; ++pr) {
                const int pA = w * 4 + pr * 2;
                const int pB = pA + 1;
                #pragma unroll
                for (int t2 = 0; t2 < 2; ++t2) {
                    const unsigned int baseo = (unsigned)(arow * 64 + t2 * 32 + hi * 8);
                    const unsigned int offA = ((unsigned)(pA * 1024) + baseo)
                                              ^ (((unsigned)((pA & 7) ^ (arow & 7))) << 4);
                    const unsigned int offB = ((unsigned)(pB * 1024) + baseo)
                                              ^ (((unsigned)((pB & 7) ^ (arow & 7))) << 4);
                    *(uint2*)(fbw + offA) = holdA[pr][t2];
                    *(uint2*)(fbw + offB) = holdB[pr][t2];
                }
            }
        }
        __syncthreads();

        #pragma unroll
        for (int m = 0; m < 16; ++m) {   // odd kk = 2m+1  (cin 32..63)
            const unsigned int xr = ((unsigned)((arow & 7) ^ (m & 7))) << 4;
            const bf16x8 av = *(const bf16x8*)(fbb +
                (((unsigned)(arow * 1024 + m * 64 + hi * 16)) ^ xr));
            const bf16x8 bv = *(const bf16x8*)(wtb + m * 64 + 32);
            acc = __builtin_amdgcn_mfma_f32_16x16x32_bf16(av, bv, acc, 0, 0, 0);
        }

        const float bvs = bias[w * 16 + arow];
        #pragma unroll
        for (int r = 0; r < 4; ++r) {
            const int prow = hi * 4 + r;
            out[((size_t)(pt0 + prow)) * 64 + w * 16 + arow] = acc[r] + bvs;
        }
    }
}

extern "C" void kernel_launch(void* const* d_in, const int* in_sizes, int n_in,
                              void* d_out, int out_size, void* d_ws, size_t ws_size,
                              hipStream_t stream) {
    const float* inp      = (const float*)d_in[0];
    const float* points   = (const float*)d_in[1];
    const float* next_pts = (const float*)d_in[2];
    const int*   indices  = (const int*)  d_in[3];
    const float* weight   = (const float*)d_in[4];
    const float* bias     = (const float*)d_in[5];
    const float* centers  = (const float*)d_in[6];
    const float* l1w      = (const float*)d_in[7];
    const float* l1b      = (const float*)d_in[8];
    const float* l2w      = (const float*)d_in[9];
    const float* l2b      = (const float*)d_in[10];
    const float* l3w      = (const float*)d_in[11];
    const float* l3b      = (const float*)d_in[12];
    float* outp = (float*)d_out;

    unsigned short* Wt    = (unsigned short*)d_ws;                  // 128 KB @ 0
    float*          A1f   = (float*)((char*)d_ws + 131072);         // 512 B
    unsigned short* Wt2   = (unsigned short*)((char*)d_ws + 132096);// 1 KB
    unsigned short* Wt3   = (unsigned short*)((char*)d_ws + 133120);// 1 KB
    unsigned short* inpbf = (unsigned short*)((char*)d_ws + (1 << 20)); // 4 MB @ 1 MB

    prep_all<<<2306, 256, 0, stream>>>(inp, inpbf, weight, Wt,
                                       l1w, l1b, centers, A1f,
                                       l2w, l3w, Wt2, Wt3);

    const int grid = (BB * NN) / P;               // 2048 blocks
    ptconv_fused<<<grid, 256, 0, stream>>>(inpbf, points, next_pts, indices,
                                           Wt, Wt2, Wt3, A1f, bias,
                                           l2b, l3b, outp);
}